// Round 11
// baseline (686.846 us; speedup 1.0000x reference)
//
#include <hip/hip_runtime.h>
#include <hip/hip_bf16.h>
#include <stdint.h>
#include <stddef.h>

// Problem constants (fixed shapes — no bounds checks needed)
#define EMBED 2048
#define TLEN  2048
#define BSZ   2
#define NH    32
#define NKV   8
#define HD    64
#define MROWS (BSZ*TLEN)   // 4096
#define KVD   (NKV*HD)     // 512

typedef __attribute__((ext_vector_type(8))) short   s16x8;
typedef __attribute__((ext_vector_type(8))) __bf16  bf16x8;
typedef __attribute__((ext_vector_type(4))) float   f32x4;

static __device__ __forceinline__ float bf2f(short u) {
  union { float f; uint32_t i; } c; c.i = ((uint32_t)(uint16_t)u) << 16; return c.f;
}
static __device__ __forceinline__ short f2bf(float f) {
  union { float f; uint32_t i; } c; c.f = f;
  uint32_t x = c.i;
  uint32_t r = (x + 0x7fffu + ((x >> 16) & 1u)) >> 16;  // RNE
  return (short)(uint16_t)r;
}
static __device__ __forceinline__ bf16x8 as_bf16x8(s16x8 s) {
  return __builtin_bit_cast(bf16x8, s);
}

// ---------------------------------------------------------------------------
// W [K][N] fp32  ->  Wt [N][K] bf16   (B^T layout for the GEMM B-fragments)
__global__ __launch_bounds__(256) void transpose_cast_kernel(
    const float* __restrict__ W, short* __restrict__ Wt, int K, int N) {
  __shared__ float tile[32][33];
  int n0 = blockIdx.x * 32, k0 = blockIdx.y * 32;
  int tx = threadIdx.x, ty = threadIdx.y;   // 32 x 8
  #pragma unroll
  for (int i = 0; i < 32; i += 8)
    tile[ty + i][tx] = W[(size_t)(k0 + ty + i) * N + n0 + tx];
  __syncthreads();
  #pragma unroll
  for (int i = 0; i < 32; i += 8)
    Wt[(size_t)(n0 + ty + i) * K + k0 + tx] = f2bf(tile[tx][ty + i]);
}

// fp32 -> bf16 elementwise (x), 4 elems/thread
__global__ __launch_bounds__(256) void cast_bf16_kernel(
    const float* __restrict__ in, short* __restrict__ out, int n) {
  int i = (blockIdx.x * blockDim.x + threadIdx.x) * 4;
  if (i >= n) return;
  f32x4 v = *(const f32x4*)(in + i);
  short o0 = f2bf(v.x), o1 = f2bf(v.y), o2 = f2bf(v.z), o3 = f2bf(v.w);
  typedef __attribute__((ext_vector_type(4))) short s16x4;
  s16x4 o = { o0, o1, o2, o3 };
  *(s16x4*)(out + i) = o;
}

// ---------------------------------------------------------------------------
// C[M=4096][N] = A[4096][2048](bf16) @ Bt[N][2048]^T (bf16) + bias
// 128x128 tile, BK=32, 4 waves (2x2 of 64x64), 4x4 fragments of 16x16x32 MFMA
template<bool OUT_F32>
__global__ __launch_bounds__(256) void gemm_bt(
    const short* __restrict__ A, const short* __restrict__ Bt,
    const float* __restrict__ bias, void* __restrict__ Cout, int N) {
  const int K = 2048;
  __shared__ __align__(16) short As[128 * 32];
  __shared__ __align__(16) short Bs[128 * 32];
  int bn = blockIdx.x, bm = blockIdx.y;
  int tid = threadIdx.x;
  int lane = tid & 63, wave = tid >> 6;
  int wr = wave >> 1, wc = wave & 1;
  int fr = lane & 15, fk = lane >> 4;
  f32x4 acc[4][4] = {};
  const short* Ab = A + (size_t)bm * 128 * K;
  const short* Bb = Bt + (size_t)bn * 128 * K;
  for (int kt = 0; kt < K; kt += 32) {
    #pragma unroll
    for (int c = tid; c < 512; c += 256) {
      int r = c >> 2, kb = (c & 3) << 3;
      *(s16x8*)&As[r * 32 + kb] = *(const s16x8*)&Ab[(size_t)r * K + kt + kb];
      *(s16x8*)&Bs[r * 32 + kb] = *(const s16x8*)&Bb[(size_t)r * K + kt + kb];
    }
    __syncthreads();
    bf16x8 af[4], bfr[4];
    #pragma unroll
    for (int m = 0; m < 4; ++m)
      af[m] = as_bf16x8(*(const s16x8*)&As[(wr * 64 + m * 16 + fr) * 32 + fk * 8]);
    #pragma unroll
    for (int n = 0; n < 4; ++n)
      bfr[n] = as_bf16x8(*(const s16x8*)&Bs[(wc * 64 + n * 16 + fr) * 32 + fk * 8]);
    #pragma unroll
    for (int m = 0; m < 4; ++m)
      #pragma unroll
      for (int n = 0; n < 4; ++n)
        acc[m][n] = __builtin_amdgcn_mfma_f32_16x16x32_bf16(af[m], bfr[n], acc[m][n], 0, 0, 0);
    __syncthreads();
  }
  int row0 = bm * 128 + wr * 64;
  int col0 = bn * 128 + wc * 64;
  #pragma unroll
  for (int n = 0; n < 4; ++n) {
    int col = col0 + n * 16 + fr;
    float bv = bias[col];
    #pragma unroll
    for (int m = 0; m < 4; ++m)
      #pragma unroll
      for (int j = 0; j < 4; ++j) {
        int row = row0 + m * 16 + fk * 4 + j;   // C/D: col=lane&15, row=(lane>>4)*4+reg
        float v = acc[m][n][j] + bv;
        if constexpr (OUT_F32) ((float*)Cout)[(size_t)row * N + col] = v;
        else                   ((short*)Cout)[(size_t)row * N + col] = f2bf(v);
      }
  }
}

// ---------------------------------------------------------------------------
// Interleaved RoPE, INVERSE rotation (matches the harness's np reference:
// measured via t=1 channel, R7-R10 — err ratios fit R(-theta), see journal).
//   x'[2i]   = x[2i]*cos + x[2i+1]*sin
//   x'[2i+1] = x[2i+1]*cos - x[2i]*sin
__global__ __launch_bounds__(256) void rope_kernel(short* __restrict__ X, int rowlen) {
  int idx = blockIdx.x * blockDim.x + threadIdx.x;
  int npr = rowlen >> 1;
  if (idx >= MROWS * npr) return;
  int row = idx / npr, cp = idx - row * npr;
  int i = cp & 31;                 // pair index within head (HD/2 = 32)
  int t = row & (TLEN - 1);        // position
  float ang = (float)t * powf(10000.0f, -(float)i / 32.0f);
  float c, s;
  sincosf(ang, &c, &s);
  short* p = X + (size_t)row * rowlen + cp * 2;
  float e = bf2f(p[0]), o = bf2f(p[1]);
  p[0] = f2bf(e * c + o * s);      // SIGN-FLIPPED vs JAX-as-written
  p[1] = f2bf(o * c - e * s);
}

// ---------------------------------------------------------------------------
// Flash attention, causal, GQA. Block: 4 waves, 64 q-rows (16/wave), KV tiles
// of 32. (Value-correctness proven: R1 output bit-matched the scalar R3/R4.)
__global__ __launch_bounds__(256) void attn_kernel(
    const short* __restrict__ Q, const short* __restrict__ Kx,
    const short* __restrict__ Vx, short* __restrict__ O) {
  int qt = blockIdx.x;             // 0..31
  int bh = blockIdx.y;             // 0..63
  int b = bh >> 5, h = bh & 31;
  int kvh = h >> 2;
  int tid = threadIdx.x;
  int lane = tid & 63, wave = tid >> 6;
  int fr = lane & 15, fk = lane >> 4;
  __shared__ __align__(16) short Ks[32][72];
  __shared__ __align__(16) short Vt[64][40];
  __shared__ __align__(16) short Pl[4][16][40];
  int q0 = qt * 64;
  const short* Qrow = Q + (size_t)(b * TLEN + q0 + wave * 16 + fr) * EMBED + h * HD;
  bf16x8 aq0 = as_bf16x8(*(const s16x8*)&Qrow[fk * 8]);
  bf16x8 aq1 = as_bf16x8(*(const s16x8*)&Qrow[32 + fk * 8]);
  f32x4 oacc[4] = {};
  float mrow[4] = { -INFINITY, -INFINITY, -INFINITY, -INFINITY };
  float lsum[4] = { 0.f, 0.f, 0.f, 0.f };
  int srow = tid >> 3, scb = (tid & 7) << 3;
  for (int kv0 = 0; kv0 < q0 + 64; kv0 += 32) {
    {
      const short* Kp = Kx + (size_t)(b * TLEN + kv0 + srow) * KVD + kvh * HD + scb;
      *(s16x8*)&Ks[srow][scb] = *(const s16x8*)Kp;
      const short* Vp = Vx + (size_t)(b * TLEN + kv0 + srow) * KVD + kvh * HD + scb;
      s16x8 vv = *(const s16x8*)Vp;
      #pragma unroll
      for (int i = 0; i < 8; ++i) Vt[scb + i][srow] = vv[i];
    }
    __syncthreads();
    if (kv0 <= q0 + wave * 16 + 15) {             // causal wave-level skip (uniform)
      f32x4 sacc[2] = {};
      #pragma unroll
      for (int nb = 0; nb < 2; ++nb) {
        bf16x8 bk0 = as_bf16x8(*(const s16x8*)&Ks[nb * 16 + fr][fk * 8]);
        bf16x8 bk1 = as_bf16x8(*(const s16x8*)&Ks[nb * 16 + fr][32 + fk * 8]);
        sacc[nb] = __builtin_amdgcn_mfma_f32_16x16x32_bf16(aq0, bk0, sacc[nb], 0, 0, 0);
        sacc[nb] = __builtin_amdgcn_mfma_f32_16x16x32_bf16(aq1, bk1, sacc[nb], 0, 0, 0);
      }
      float alpha[4];
      #pragma unroll
      for (int j = 0; j < 4; ++j) {
        int qg = q0 + wave * 16 + fk * 4 + j;
        float s0 = sacc[0][j] * 0.125f;
        float s1 = sacc[1][j] * 0.125f;
        if (kv0 + fr > qg)      s0 = -INFINITY;
        if (kv0 + 16 + fr > qg) s1 = -INFINITY;
        float pm = fmaxf(s0, s1);
        pm = fmaxf(pm, __shfl_xor(pm, 1, 64));
        pm = fmaxf(pm, __shfl_xor(pm, 2, 64));
        pm = fmaxf(pm, __shfl_xor(pm, 4, 64));
        pm = fmaxf(pm, __shfl_xor(pm, 8, 64));
        float mnew = fmaxf(mrow[j], pm);
        float p0 = __expf(s0 - mnew);
        float p1 = __expf(s1 - mnew);
        float rs = p0 + p1;
        rs += __shfl_xor(rs, 1, 64);
        rs += __shfl_xor(rs, 2, 64);
        rs += __shfl_xor(rs, 4, 64);
        rs += __shfl_xor(rs, 8, 64);
        float al = __expf(mrow[j] - mnew);
        lsum[j] = lsum[j] * al + rs;
        mrow[j] = mnew;
        alpha[j] = al;
        Pl[wave][fk * 4 + j][fr]      = f2bf(p0);
        Pl[wave][fk * 4 + j][16 + fr] = f2bf(p1);
      }
      #pragma unroll
      for (int db = 0; db < 4; ++db) {
        oacc[db][0] *= alpha[0]; oacc[db][1] *= alpha[1];
        oacc[db][2] *= alpha[2]; oacc[db][3] *= alpha[3];
      }
      bf16x8 ap = as_bf16x8(*(const s16x8*)&Pl[wave][fr][fk * 8]);
      #pragma unroll
      for (int db = 0; db < 4; ++db) {
        bf16x8 bv = as_bf16x8(*(const s16x8*)&Vt[db * 16 + fr][fk * 8]);
        oacc[db] = __builtin_amdgcn_mfma_f32_16x16x32_bf16(ap, bv, oacc[db], 0, 0, 0);
      }
    }
    __syncthreads();
  }
  #pragma unroll
  for (int db = 0; db < 4; ++db)
    #pragma unroll
    for (int j = 0; j < 4; ++j) {
      int qg = q0 + wave * 16 + fk * 4 + j;
      float v = oacc[db][j] / lsum[j];
      O[(size_t)(b * TLEN + qg) * EMBED + h * HD + db * 16 + fr] = f2bf(v);
    }
}

// ---------------------------------------------------------------------------
extern "C" void kernel_launch(void* const* d_in, const int* in_sizes, int n_in,
                              void* d_out, int out_size, void* d_ws, size_t ws_size,
                              hipStream_t stream) {
  const float* x  = (const float*)d_in[0];
  const float* Wq = (const float*)d_in[1];
  const float* bq = (const float*)d_in[2];
  const float* Wk = (const float*)d_in[3];
  const float* bk = (const float*)d_in[4];
  const float* Wv = (const float*)d_in[5];
  const float* bv = (const float*)d_in[6];
  const float* Wo = (const float*)d_in[7];
  const float* bo = (const float*)d_in[8];
  float* out = (float*)d_out;

  // ws layout (~63 MB; validated ws_size >= 62,914,560 by R6 probe)
  char* ws = (char*)d_ws;
  short* xb  = (short*)(ws);                // 16,777,216
  short* WqT = (short*)(ws + 16777216);     //  8,388,608
  short* WkT = (short*)(ws + 25165824);     //  2,097,152
  short* WvT = (short*)(ws + 27262976);     //  2,097,152
  short* WoT = (short*)(ws + 29360128);     //  8,388,608
  short* Qb  = (short*)(ws + 37748736);     // 16,777,216
  short* Kb  = (short*)(ws + 54525952);     //  4,194,304
  short* Vb  = (short*)(ws + 58720256);     //  4,194,304
  short* Ob  = (short*)(ws);                // alias xb (dead after QKV GEMMs)

  dim3 tb(32, 8);
  transpose_cast_kernel<<<dim3(EMBED / 32, EMBED / 32), tb, 0, stream>>>(Wq, WqT, EMBED, EMBED);
  transpose_cast_kernel<<<dim3(KVD / 32, EMBED / 32), tb, 0, stream>>>(Wk, WkT, EMBED, KVD);
  transpose_cast_kernel<<<dim3(KVD / 32, EMBED / 32), tb, 0, stream>>>(Wv, WvT, EMBED, KVD);
  transpose_cast_kernel<<<dim3(EMBED / 32, EMBED / 32), tb, 0, stream>>>(Wo, WoT, EMBED, EMBED);
  cast_bf16_kernel<<<(MROWS * EMBED / 4) / 256, 256, 0, stream>>>(x, xb, MROWS * EMBED);

  gemm_bt<false><<<dim3(EMBED / 128, MROWS / 128), 256, 0, stream>>>(xb, WqT, bq, Qb, EMBED);
  gemm_bt<false><<<dim3(KVD / 128, MROWS / 128), 256, 0, stream>>>(xb, WkT, bk, Kb, KVD);
  gemm_bt<false><<<dim3(KVD / 128, MROWS / 128), 256, 0, stream>>>(xb, WvT, bv, Vb, KVD);

  rope_kernel<<<(MROWS * (EMBED / 2)) / 256, 256, 0, stream>>>(Qb, EMBED);
  rope_kernel<<<(MROWS * (KVD / 2)) / 256, 256, 0, stream>>>(Kb, KVD);

  attn_kernel<<<dim3(TLEN / 64, BSZ * NH), 256, 0, stream>>>(Qb, Kb, Vb, Ob);

  gemm_bt<true><<<dim3(EMBED / 128, MROWS / 128), 256, 0, stream>>>(Ob, WoT, bo, out, EMBED);
}

// Round 12
// 359.142 us; speedup vs baseline: 1.9125x; 1.9125x over previous
//
#include <hip/hip_runtime.h>
#include <hip/hip_bf16.h>
#include <stdint.h>
#include <stddef.h>

#define EMBED 2048
#define TLEN  2048
#define BSZ   2
#define NH    32
#define NKV   8
#define HD    64
#define MROWS (BSZ*TLEN)   // 4096
#define KVD   (NKV*HD)     // 512

typedef __attribute__((ext_vector_type(8))) short   s16x8;
typedef __attribute__((ext_vector_type(4))) short   s16x4;
typedef __attribute__((ext_vector_type(8))) __bf16  bf16x8;
typedef __attribute__((ext_vector_type(4))) float   f32x4;
typedef __attribute__((ext_vector_type(2))) unsigned long long u64x2;

static __device__ __forceinline__ float bf2f(short u) {
  union { float f; uint32_t i; } c; c.i = ((uint32_t)(uint16_t)u) << 16; return c.f;
}
static __device__ __forceinline__ short f2bf(float f) {
  union { float f; uint32_t i; } c; c.f = f;
  uint32_t x = c.i;
  uint32_t r = (x + 0x7fffu + ((x >> 16) & 1u)) >> 16;  // RNE
  return (short)(uint16_t)r;
}
static __device__ __forceinline__ bf16x8 as_bf16x8(s16x8 s) {
  return __builtin_bit_cast(bf16x8, s);
}
static __device__ __forceinline__ bf16x8 mk8(unsigned long long a, unsigned long long b) {
  u64x2 t; t.x = a; t.y = b;
  return __builtin_bit_cast(bf16x8, t);
}

// ---------------------------------------------------------------------------
// W [K][N] fp32  ->  Wt [N][K] bf16
__global__ __launch_bounds__(256) void transpose_cast_kernel(
    const float* __restrict__ W, short* __restrict__ Wt, int K, int N) {
  __shared__ float tile[32][33];
  int n0 = blockIdx.x * 32, k0 = blockIdx.y * 32;
  int tx = threadIdx.x, ty = threadIdx.y;   // 32 x 8
  #pragma unroll
  for (int i = 0; i < 32; i += 8)
    tile[ty + i][tx] = W[(size_t)(k0 + ty + i) * N + n0 + tx];
  __syncthreads();
  #pragma unroll
  for (int i = 0; i < 32; i += 8)
    Wt[(size_t)(n0 + ty + i) * K + k0 + tx] = f2bf(tile[tx][ty + i]);
}

// fp32 -> bf16 elementwise
__global__ __launch_bounds__(256) void cast_bf16_kernel(
    const float* __restrict__ in, short* __restrict__ out, int n) {
  int i = (blockIdx.x * blockDim.x + threadIdx.x) * 4;
  if (i >= n) return;
  f32x4 v = *(const f32x4*)(in + i);
  s16x4 o = { f2bf(v.x), f2bf(v.y), f2bf(v.z), f2bf(v.w) };
  *(s16x4*)(out + i) = o;
}

// ---------------------------------------------------------------------------
// C[M=4096][N] = A @ Bt^T + bias. 128x128 tile, BK=32, 4 waves, 16x16x32 MFMA.
// Staging via global_load_lds width=16 (linear LDS dest, wave-uniform base).
template<bool OUT_F32>
__global__ __launch_bounds__(256) void gemm_bt(
    const short* __restrict__ A, const short* __restrict__ Bt,
    const float* __restrict__ bias, void* __restrict__ Cout, int N) {
  const int K = 2048;
  __shared__ __align__(16) short As[128 * 32];
  __shared__ __align__(16) short Bs[128 * 32];
  int bn = blockIdx.x, bm = blockIdx.y;
  int tid = threadIdx.x;
  int lane = tid & 63, wave = tid >> 6;
  int wr = wave >> 1, wc = wave & 1;
  int fr = lane & 15, fk = lane >> 4;
  f32x4 acc[4][4] = {};
  const short* Ab = A + (size_t)bm * 128 * K;
  const short* Bb = Bt + (size_t)bn * 128 * K;
  for (int kt = 0; kt < K; kt += 32) {
    #pragma unroll
    for (int ii = 0; ii < 2; ++ii) {
      const int i = wave * 2 + ii;                 // 0..7 (wave-uniform)
      const int r = i * 16 + (lane >> 2);
      const int c = lane & 3;
      const size_t go = (size_t)r * K + kt + c * 8;
      __builtin_amdgcn_global_load_lds(
          (const __attribute__((address_space(1))) void*)(Ab + go),
          (__attribute__((address_space(3))) void*)&As[i * 512], 16, 0, 0);
      __builtin_amdgcn_global_load_lds(
          (const __attribute__((address_space(1))) void*)(Bb + go),
          (__attribute__((address_space(3))) void*)&Bs[i * 512], 16, 0, 0);
    }
    __syncthreads();
    bf16x8 af[4], bfr[4];
    #pragma unroll
    for (int m = 0; m < 4; ++m)
      af[m] = as_bf16x8(*(const s16x8*)&As[(wr * 64 + m * 16 + fr) * 32 + fk * 8]);
    #pragma unroll
    for (int n = 0; n < 4; ++n)
      bfr[n] = as_bf16x8(*(const s16x8*)&Bs[(wc * 64 + n * 16 + fr) * 32 + fk * 8]);
    #pragma unroll
    for (int m = 0; m < 4; ++m)
      #pragma unroll
      for (int n = 0; n < 4; ++n)
        acc[m][n] = __builtin_amdgcn_mfma_f32_16x16x32_bf16(af[m], bfr[n], acc[m][n], 0, 0, 0);
    __syncthreads();
  }
  int row0 = bm * 128 + wr * 64;
  int col0 = bn * 128 + wc * 64;
  #pragma unroll
  for (int n = 0; n < 4; ++n) {
    int col = col0 + n * 16 + fr;
    float bv = bias[col];
    #pragma unroll
    for (int m = 0; m < 4; ++m)
      #pragma unroll
      for (int j = 0; j < 4; ++j) {
        int row = row0 + m * 16 + fk * 4 + j;
        float v = acc[m][n][j] + bv;
        if constexpr (OUT_F32) ((float*)Cout)[(size_t)row * N + col] = v;
        else                   ((short*)Cout)[(size_t)row * N + col] = f2bf(v);
      }
  }
}

// ---------------------------------------------------------------------------
// Interleaved RoPE, INVERSE rotation (np reference convention, verified R11),
// with optional exact pow2 output scale (folds the 1/sqrt(64) into Q).
__global__ __launch_bounds__(256) void rope_kernel(short* __restrict__ X, int rowlen,
                                                   float oscale) {
  int idx = blockIdx.x * blockDim.x + threadIdx.x;
  int npr = rowlen >> 1;
  if (idx >= MROWS * npr) return;
  int row = idx / npr, cp = idx - row * npr;
  int i = cp & 31;
  int t = row & (TLEN - 1);
  float ang = (float)t * powf(10000.0f, -(float)i / 32.0f);
  float c, s;
  sincosf(ang, &c, &s);
  short* p = X + (size_t)row * rowlen + cp * 2;
  float e = bf2f(p[0]), o = bf2f(p[1]);
  p[0] = f2bf((e * c + o * s) * oscale);
  p[1] = f2bf((o * c - e * s) * oscale);
}

// ---------------------------------------------------------------------------
// Flash attention, causal, GQA. Block = 4 waves, 64 q-rows (16/wave),
// KVBLK=64. Each block processes the q-tile PAIR (p, 31-p): uniform 33
// tiles/block (load balance). V staged into tr-read subtiled LDS
// ([d0b][g][4][16], conflict-free writes), consumed via ds_read_b64_tr_b16.
// Q pre-scaled by 1/8 in rope.
__global__ __launch_bounds__(256) void attn_kernel(
    const short* __restrict__ Q, const short* __restrict__ Kx,
    const short* __restrict__ Vx, short* __restrict__ O) {
  const int pr = blockIdx.x;           // 0..15
  const int bh = blockIdx.y;           // 0..63
  const int b = bh >> 5, h = bh & 31, kvh = h >> 2;
  const int tid = threadIdx.x;
  const int lane = tid & 63, wave = tid >> 6;
  const int fr = lane & 15, fk = lane >> 4;

  __shared__ __align__(16) short Ks[64][72];    // row stride 144B (16B-mult, 2-way)
  __shared__ __align__(16) short VS[4 * 1040];  // [d0b][g:16][4][16], d0b stride 1040
  __shared__ __align__(16) short Pl[4][16][72];

  const short* Kbase = Kx + (size_t)b * TLEN * KVD + kvh * HD;
  const short* Vbase = Vx + (size_t)b * TLEN * KVD + kvh * HD;

  const int srow = tid >> 3;           // 0..31
  const int scb  = (tid & 7) << 3;     // 0..56 (shorts)
  const int vd0  = scb >> 4;           // d0-block 0..3
  const int vco  = scb & 15;           // 0 or 8
  const unsigned trb = (unsigned)(unsigned long long)&VS[fk * 128 + fr * 4];
  const int rowq = wave * 16 + fk * 4; // for causal mask on the diagonal tile

#define TRREAD(dst, OFF) asm volatile("ds_read_b64_tr_b16 %0, %1 offset:" OFF \
    : "=v"(dst) : "v"(trb) : "memory")

  #pragma unroll 1
  for (int rep = 0; rep < 2; ++rep) {
    const int qt = rep ? (31 - pr) : pr;
    const int q0 = qt * 64;
    const short* Qrow = Q + (size_t)(b * TLEN + q0 + wave * 16 + fr) * EMBED + h * HD;
    const bf16x8 aq0 = as_bf16x8(*(const s16x8*)&Qrow[fk * 8]);
    const bf16x8 aq1 = as_bf16x8(*(const s16x8*)&Qrow[32 + fk * 8]);
    f32x4 oacc[4] = {};
    float mrow[4] = { -INFINITY, -INFINITY, -INFINITY, -INFINITY };
    float lsum[4] = { 0.f, 0.f, 0.f, 0.f };

    for (int kv0 = 0; kv0 <= q0; kv0 += 64) {
      // ---- stage K (row-major padded) and V (subtiled) ----
      #pragma unroll
      for (int it = 0; it < 2; ++it) {
        const int r = srow + it * 32;
        const size_t gro = (size_t)(kv0 + r) * KVD + scb;
        *(s16x8*)&Ks[r][scb] = *(const s16x8*)&Kbase[gro];
        s16x8 vv = *(const s16x8*)&Vbase[gro];
        *(s16x8*)&VS[vd0 * 1040 + ((r >> 2) << 6) + ((r & 3) << 4) + vco] = vv;
      }
      __syncthreads();

      // ---- S = Q K^T : 4 n-tiles, K=64 ----
      f32x4 sacc[4] = {};
      #pragma unroll
      for (int nb = 0; nb < 4; ++nb) {
        bf16x8 bk0 = as_bf16x8(*(const s16x8*)&Ks[nb * 16 + fr][fk * 8]);
        bf16x8 bk1 = as_bf16x8(*(const s16x8*)&Ks[nb * 16 + fr][32 + fk * 8]);
        sacc[nb] = __builtin_amdgcn_mfma_f32_16x16x32_bf16(aq0, bk0, sacc[nb], 0, 0, 0);
        sacc[nb] = __builtin_amdgcn_mfma_f32_16x16x32_bf16(aq1, bk1, sacc[nb], 0, 0, 0);
      }
      const bool diag = (kv0 == q0);

      // ---- online softmax (rows = fk*4+j), write P to LDS ----
      float alpha[4];
      #pragma unroll
      for (int j = 0; j < 4; ++j) {
        float v0 = sacc[0][j], v1 = sacc[1][j], v2 = sacc[2][j], v3 = sacc[3][j];
        if (diag) {
          const int thr = rowq + j;
          if (fr > thr)      v0 = -INFINITY;
          if (16 + fr > thr) v1 = -INFINITY;
          if (32 + fr > thr) v2 = -INFINITY;
          if (48 + fr > thr) v3 = -INFINITY;
        }
        float pm = fmaxf(fmaxf(v0, v1), fmaxf(v2, v3));
        pm = fmaxf(pm, __shfl_xor(pm, 1, 64));
        pm = fmaxf(pm, __shfl_xor(pm, 2, 64));
        pm = fmaxf(pm, __shfl_xor(pm, 4, 64));
        pm = fmaxf(pm, __shfl_xor(pm, 8, 64));
        const float mnew = fmaxf(mrow[j], pm);
        const float p0 = __expf(v0 - mnew);
        const float p1 = __expf(v1 - mnew);
        const float p2 = __expf(v2 - mnew);
        const float p3 = __expf(v3 - mnew);
        float rs = (p0 + p1) + (p2 + p3);
        rs += __shfl_xor(rs, 1, 64);
        rs += __shfl_xor(rs, 2, 64);
        rs += __shfl_xor(rs, 4, 64);
        rs += __shfl_xor(rs, 8, 64);
        const float al = __expf(mrow[j] - mnew);
        lsum[j] = lsum[j] * al + rs;
        mrow[j] = mnew;
        alpha[j] = al;
        short* prow = &Pl[wave][fk * 4 + j][fr];
        prow[0]  = f2bf(p0);
        prow[16] = f2bf(p1);
        prow[32] = f2bf(p2);
        prow[48] = f2bf(p3);
      }

      // ---- rescale O, then PV with tr-read V fragments ----
      #pragma unroll
      for (int db = 0; db < 4; ++db) {
        oacc[db][0] *= alpha[0]; oacc[db][1] *= alpha[1];
        oacc[db][2] *= alpha[2]; oacc[db][3] *= alpha[3];
      }
      const bf16x8 ap0 = as_bf16x8(*(const s16x8*)&Pl[wave][fr][fk * 8]);
      const bf16x8 ap1 = as_bf16x8(*(const s16x8*)&Pl[wave][fr][32 + fk * 8]);
      unsigned long long t00, t01, t02, t03, t10, t11, t12, t13;
      unsigned long long t20, t21, t22, t23, t30, t31, t32, t33;
      TRREAD(t00, "0");    TRREAD(t01, "128");  TRREAD(t02, "1024"); TRREAD(t03, "1152");
      TRREAD(t10, "2080"); TRREAD(t11, "2208"); TRREAD(t12, "3104"); TRREAD(t13, "3232");
      TRREAD(t20, "4160"); TRREAD(t21, "4288"); TRREAD(t22, "5184"); TRREAD(t23, "5312");
      TRREAD(t30, "6240"); TRREAD(t31, "6368"); TRREAD(t32, "7264"); TRREAD(t33, "7392");
      asm volatile("s_waitcnt lgkmcnt(0)" ::: "memory");
      __builtin_amdgcn_sched_barrier(0);
      oacc[0] = __builtin_amdgcn_mfma_f32_16x16x32_bf16(ap0, mk8(t00, t01), oacc[0], 0, 0, 0);
      oacc[0] = __builtin_amdgcn_mfma_f32_16x16x32_bf16(ap1, mk8(t02, t03), oacc[0], 0, 0, 0);
      oacc[1] = __builtin_amdgcn_mfma_f32_16x16x32_bf16(ap0, mk8(t10, t11), oacc[1], 0, 0, 0);
      oacc[1] = __builtin_amdgcn_mfma_f32_16x16x32_bf16(ap1, mk8(t12, t13), oacc[1], 0, 0, 0);
      oacc[2] = __builtin_amdgcn_mfma_f32_16x16x32_bf16(ap0, mk8(t20, t21), oacc[2], 0, 0, 0);
      oacc[2] = __builtin_amdgcn_mfma_f32_16x16x32_bf16(ap1, mk8(t22, t23), oacc[2], 0, 0, 0);
      oacc[3] = __builtin_amdgcn_mfma_f32_16x16x32_bf16(ap0, mk8(t30, t31), oacc[3], 0, 0, 0);
      oacc[3] = __builtin_amdgcn_mfma_f32_16x16x32_bf16(ap1, mk8(t32, t33), oacc[3], 0, 0, 0);
      __syncthreads();
    }

    // ---- epilogue for this q-tile ----
    #pragma unroll
    for (int db = 0; db < 4; ++db)
      #pragma unroll
      for (int j = 0; j < 4; ++j) {
        const int qg = q0 + wave * 16 + fk * 4 + j;
        O[(size_t)(b * TLEN + qg) * EMBED + h * HD + db * 16 + fr] =
            f2bf(oacc[db][j] / lsum[j]);
      }
  }
#undef TRREAD
}

// ---------------------------------------------------------------------------
extern "C" void kernel_launch(void* const* d_in, const int* in_sizes, int n_in,
                              void* d_out, int out_size, void* d_ws, size_t ws_size,
                              hipStream_t stream) {
  const float* x  = (const float*)d_in[0];
  const float* Wq = (const float*)d_in[1];
  const float* bq = (const float*)d_in[2];
  const float* Wk = (const float*)d_in[3];
  const float* bk = (const float*)d_in[4];
  const float* Wv = (const float*)d_in[5];
  const float* bv = (const float*)d_in[6];
  const float* Wo = (const float*)d_in[7];
  const float* bo = (const float*)d_in[8];
  float* out = (float*)d_out;

  char* ws = (char*)d_ws;
  short* xb  = (short*)(ws);                // 16,777,216
  short* WqT = (short*)(ws + 16777216);     //  8,388,608
  short* WkT = (short*)(ws + 25165824);     //  2,097,152
  short* WvT = (short*)(ws + 27262976);     //  2,097,152
  short* WoT = (short*)(ws + 29360128);     //  8,388,608
  short* Qb  = (short*)(ws + 37748736);     // 16,777,216
  short* Kb  = (short*)(ws + 54525952);     //  4,194,304
  short* Vb  = (short*)(ws + 58720256);     //  4,194,304
  short* Ob  = (short*)(ws);                // alias xb (dead after QKV GEMMs)

  dim3 tb(32, 8);
  transpose_cast_kernel<<<dim3(EMBED / 32, EMBED / 32), tb, 0, stream>>>(Wq, WqT, EMBED, EMBED);
  transpose_cast_kernel<<<dim3(KVD / 32, EMBED / 32), tb, 0, stream>>>(Wk, WkT, EMBED, KVD);
  transpose_cast_kernel<<<dim3(KVD / 32, EMBED / 32), tb, 0, stream>>>(Wv, WvT, EMBED, KVD);
  transpose_cast_kernel<<<dim3(EMBED / 32, EMBED / 32), tb, 0, stream>>>(Wo, WoT, EMBED, EMBED);
  cast_bf16_kernel<<<(MROWS * EMBED / 4) / 256, 256, 0, stream>>>(x, xb, MROWS * EMBED);

  gemm_bt<false><<<dim3(EMBED / 128, MROWS / 128), 256, 0, stream>>>(xb, WqT, bq, Qb, EMBED);
  gemm_bt<false><<<dim3(KVD / 128, MROWS / 128), 256, 0, stream>>>(xb, WkT, bk, Kb, KVD);
  gemm_bt<false><<<dim3(KVD / 128, MROWS / 128), 256, 0, stream>>>(xb, WvT, bv, Vb, KVD);

  rope_kernel<<<(MROWS * (EMBED / 2)) / 256, 256, 0, stream>>>(Qb, EMBED, 0.125f);
  rope_kernel<<<(MROWS * (KVD / 2)) / 256, 256, 0, stream>>>(Kb, KVD, 1.0f);

  attn_kernel<<<dim3(16, BSZ * NH), 256, 0, stream>>>(Qb, Kb, Vb, Ob);

  gemm_bt<true><<<dim3(EMBED / 128, MROWS / 128), 256, 0, stream>>>(Ob, WoT, bo, out, EMBED);
}

// Round 13
// 267.886 us; speedup vs baseline: 2.5639x; 1.3407x over previous
//
#include <hip/hip_runtime.h>
#include <hip/hip_bf16.h>
#include <stdint.h>
#include <stddef.h>

#define EMBED 2048
#define TLEN  2048
#define BSZ   2
#define NH    32
#define NKV   8
#define HD    64
#define MROWS (BSZ*TLEN)   // 4096
#define KVD   (NKV*HD)     // 512
#define QKVN  3072         // fused QKV column extent / row stride

typedef __attribute__((ext_vector_type(8))) short   s16x8;
typedef __attribute__((ext_vector_type(4))) short   s16x4;
typedef __attribute__((ext_vector_type(8))) __bf16  bf16x8;
typedef __attribute__((ext_vector_type(4))) float   f32x4;
typedef __attribute__((ext_vector_type(2))) unsigned long long u64x2;

static __device__ __forceinline__ float bf2f(short u) {
  union { float f; uint32_t i; } c; c.i = ((uint32_t)(uint16_t)u) << 16; return c.f;
}
static __device__ __forceinline__ short f2bf(float f) {
  union { float f; uint32_t i; } c; c.f = f;
  uint32_t x = c.i;
  uint32_t r = (x + 0x7fffu + ((x >> 16) & 1u)) >> 16;  // RNE
  return (short)(uint16_t)r;
}
static __device__ __forceinline__ bf16x8 as_bf16x8(s16x8 s) {
  return __builtin_bit_cast(bf16x8, s);
}
static __device__ __forceinline__ bf16x8 mk8(unsigned long long a, unsigned long long b) {
  u64x2 t; t.x = a; t.y = b;
  return __builtin_bit_cast(bf16x8, t);
}

// ---------------------------------------------------------------------------
// W [K][N] fp32  ->  Wt [N][K] bf16 (dst base may carry a row offset)
__global__ __launch_bounds__(256) void transpose_cast_kernel(
    const float* __restrict__ W, short* __restrict__ Wt, int K, int N) {
  __shared__ float tile[32][33];
  int n0 = blockIdx.x * 32, k0 = blockIdx.y * 32;
  int tx = threadIdx.x, ty = threadIdx.y;   // 32 x 8
  #pragma unroll
  for (int i = 0; i < 32; i += 8)
    tile[ty + i][tx] = W[(size_t)(k0 + ty + i) * N + n0 + tx];
  __syncthreads();
  #pragma unroll
  for (int i = 0; i < 32; i += 8)
    Wt[(size_t)(n0 + ty + i) * K + k0 + tx] = f2bf(tile[tx][ty + i]);
}

// fp32 -> bf16 elementwise
__global__ __launch_bounds__(256) void cast_bf16_kernel(
    const float* __restrict__ in, short* __restrict__ out, int n) {
  int i = (blockIdx.x * blockDim.x + threadIdx.x) * 4;
  if (i >= n) return;
  f32x4 v = *(const f32x4*)(in + i);
  s16x4 o = { f2bf(v.x), f2bf(v.y), f2bf(v.z), f2bf(v.w) };
  *(s16x4*)(out + i) = o;
}

// ---------------------------------------------------------------------------
// C[M=4096][colN] = A[4096][2048] @ Bt[colN][2048]^T + bias; row stride ldc.
// 128x128 tile, BK=32, 4 waves, global_load_lds width=16 staging.
// TRIPLE_BIAS: bias = concat(b0[2048], b1[512], b2[512]) selected by col.
template<bool OUT_F32, bool TRIPLE_BIAS>
__global__ __launch_bounds__(256) void gemm_bt(
    const short* __restrict__ A, const short* __restrict__ Bt,
    const float* __restrict__ b0, const float* __restrict__ b1,
    const float* __restrict__ b2, void* __restrict__ Cout, int ldc) {
  const int K = 2048;
  __shared__ __align__(16) short As[128 * 32];
  __shared__ __align__(16) short Bs[128 * 32];
  int bn = blockIdx.x, bm = blockIdx.y;
  int tid = threadIdx.x;
  int lane = tid & 63, wave = tid >> 6;
  int wr = wave >> 1, wc = wave & 1;
  int fr = lane & 15, fk = lane >> 4;
  f32x4 acc[4][4] = {};
  const short* Ab = A + (size_t)bm * 128 * K;
  const short* Bb = Bt + (size_t)bn * 128 * K;
  for (int kt = 0; kt < K; kt += 32) {
    #pragma unroll
    for (int ii = 0; ii < 2; ++ii) {
      const int i = wave * 2 + ii;
      const int r = i * 16 + (lane >> 2);
      const int c = lane & 3;
      const size_t go = (size_t)r * K + kt + c * 8;
      __builtin_amdgcn_global_load_lds(
          (const __attribute__((address_space(1))) void*)(Ab + go),
          (__attribute__((address_space(3))) void*)&As[i * 512], 16, 0, 0);
      __builtin_amdgcn_global_load_lds(
          (const __attribute__((address_space(1))) void*)(Bb + go),
          (__attribute__((address_space(3))) void*)&Bs[i * 512], 16, 0, 0);
    }
    __syncthreads();
    bf16x8 af[4], bfr[4];
    #pragma unroll
    for (int m = 0; m < 4; ++m)
      af[m] = as_bf16x8(*(const s16x8*)&As[(wr * 64 + m * 16 + fr) * 32 + fk * 8]);
    #pragma unroll
    for (int n = 0; n < 4; ++n)
      bfr[n] = as_bf16x8(*(const s16x8*)&Bs[(wc * 64 + n * 16 + fr) * 32 + fk * 8]);
    __builtin_amdgcn_s_setprio(1);
    #pragma unroll
    for (int m = 0; m < 4; ++m)
      #pragma unroll
      for (int n = 0; n < 4; ++n)
        acc[m][n] = __builtin_amdgcn_mfma_f32_16x16x32_bf16(af[m], bfr[n], acc[m][n], 0, 0, 0);
    __builtin_amdgcn_s_setprio(0);
    __syncthreads();
  }
  int row0 = bm * 128 + wr * 64;
  int col0 = bn * 128 + wc * 64;
  #pragma unroll
  for (int n = 0; n < 4; ++n) {
    int col = col0 + n * 16 + fr;
    float bv;
    if constexpr (TRIPLE_BIAS)
      bv = (col < 2048) ? b0[col] : ((col < 2560) ? b1[col - 2048] : b2[col - 2560]);
    else
      bv = b0[col];
    #pragma unroll
    for (int m = 0; m < 4; ++m)
      #pragma unroll
      for (int j = 0; j < 4; ++j) {
        int row = row0 + m * 16 + fk * 4 + j;
        float v = acc[m][n][j] + bv;
        if constexpr (OUT_F32) ((float*)Cout)[(size_t)row * ldc + col] = v;
        else                   ((short*)Cout)[(size_t)row * ldc + col] = f2bf(v);
      }
  }
}

// ---------------------------------------------------------------------------
// RoPE cos/sin table: tab[t*32+i] = {cos, sin}(t * 10000^(-i/32)), t<2048,i<32
__global__ __launch_bounds__(256) void rope_table_kernel(float2* __restrict__ tab) {
  int idx = blockIdx.x * 256 + threadIdx.x;       // 0..65535
  int t = idx >> 5, i = idx & 31;
  float ang = (float)t * powf(10000.0f, -(float)i / 32.0f);
  float c, s;
  sincosf(ang, &c, &s);
  tab[idx] = make_float2(c, s);
}

// Interleaved RoPE, INVERSE rotation (np reference convention, verified R11),
// table-driven, optional pow2 scale. X base may carry a column offset; row
// stride ldx, ncols columns (multiple of 64).
__global__ __launch_bounds__(256) void rope_apply_kernel(
    short* __restrict__ X, int ncols, int ldx, float oscale,
    const float2* __restrict__ tab) {
  int idx = blockIdx.x * 256 + threadIdx.x;
  int npr = ncols >> 1;
  int row = idx / npr, cp = idx - row * npr;
  int i = cp & 31;
  int t = row & (TLEN - 1);
  float2 cs = tab[(t << 5) | i];
  short* p = X + (size_t)row * ldx + cp * 2;
  float e = bf2f(p[0]), o = bf2f(p[1]);
  p[0] = f2bf((e * cs.x + o * cs.y) * oscale);
  p[1] = f2bf((o * cs.x - e * cs.y) * oscale);
}

// ---------------------------------------------------------------------------
// Flash attention, causal, GQA. 4 waves, 64 q-rows/block, KVBLK=64, q-tile
// pair (p, 31-p) per block. Q/K/V in packed QKV buffer (row stride 3072).
// lsum via ones-column MFMA (no sum shfl-reduce); defer-max (THR=8); setprio.
__global__ __launch_bounds__(256) void attn_kernel(
    const short* __restrict__ Q, const short* __restrict__ Kx,
    const short* __restrict__ Vx, short* __restrict__ O) {
  const int pr = blockIdx.x;           // 0..15
  const int bh = blockIdx.y;           // 0..63
  const int b = bh >> 5, h = bh & 31, kvh = h >> 2;
  const int tid = threadIdx.x;
  const int lane = tid & 63, wave = tid >> 6;
  const int fr = lane & 15, fk = lane >> 4;

  __shared__ __align__(16) short Ks[64][72];
  __shared__ __align__(16) short VS[4 * 1040];
  __shared__ __align__(16) short Pl[4][16][72];

  const short* Kbase = Kx + (size_t)b * TLEN * QKVN + kvh * HD;
  const short* Vbase = Vx + (size_t)b * TLEN * QKVN + kvh * HD;

  const int srow = tid >> 3;
  const int scb  = (tid & 7) << 3;
  const int vd0  = scb >> 4;
  const int vco  = scb & 15;
  const unsigned trb = (unsigned)(unsigned long long)&VS[fk * 128 + fr * 4];
  const int rowq = wave * 16 + fk * 4;
  const bf16x8 ones = mk8(0x3F803F803F803F80ULL, 0x3F803F803F803F80ULL);

#define TRREAD(dst, OFF) asm volatile("ds_read_b64_tr_b16 %0, %1 offset:" OFF \
    : "=v"(dst) : "v"(trb) : "memory")

  #pragma unroll 1
  for (int rep = 0; rep < 2; ++rep) {
    const int qt = rep ? (31 - pr) : pr;
    const int q0 = qt * 64;
    const short* Qrow = Q + (size_t)(b * TLEN + q0 + wave * 16 + fr) * QKVN + h * HD;
    const bf16x8 aq0 = as_bf16x8(*(const s16x8*)&Qrow[fk * 8]);
    const bf16x8 aq1 = as_bf16x8(*(const s16x8*)&Qrow[32 + fk * 8]);
    f32x4 oacc[4] = {};
    f32x4 lacc = {};
    float mrow[4] = { -INFINITY, -INFINITY, -INFINITY, -INFINITY };

    for (int kv0 = 0; kv0 <= q0; kv0 += 64) {
      // ---- stage K (row-major padded) and V (tr-read subtiled) ----
      #pragma unroll
      for (int it = 0; it < 2; ++it) {
        const int r = srow + it * 32;
        const size_t gro = (size_t)(kv0 + r) * QKVN + scb;
        *(s16x8*)&Ks[r][scb] = *(const s16x8*)&Kbase[gro];
        s16x8 vv = *(const s16x8*)&Vbase[gro];
        *(s16x8*)&VS[vd0 * 1040 + ((r >> 2) << 6) + ((r & 3) << 4) + vco] = vv;
      }
      __syncthreads();

      // ---- S = Q K^T : 4 n-tiles, K=64 ----
      f32x4 sacc[4] = {};
      {
        bf16x8 bk0[4], bk1[4];
        #pragma unroll
        for (int nb = 0; nb < 4; ++nb) {
          bk0[nb] = as_bf16x8(*(const s16x8*)&Ks[nb * 16 + fr][fk * 8]);
          bk1[nb] = as_bf16x8(*(const s16x8*)&Ks[nb * 16 + fr][32 + fk * 8]);
        }
        __builtin_amdgcn_s_setprio(1);
        #pragma unroll
        for (int nb = 0; nb < 4; ++nb) {
          sacc[nb] = __builtin_amdgcn_mfma_f32_16x16x32_bf16(aq0, bk0[nb], sacc[nb], 0, 0, 0);
          sacc[nb] = __builtin_amdgcn_mfma_f32_16x16x32_bf16(aq1, bk1[nb], sacc[nb], 0, 0, 0);
        }
        __builtin_amdgcn_s_setprio(0);
      }
      const bool diag = (kv0 == q0);

      // ---- masked scores + row-max reduce ----
      float sv[4][4];
      float pmj[4];
      #pragma unroll
      for (int j = 0; j < 4; ++j) {
        float v0 = sacc[0][j], v1 = sacc[1][j], v2 = sacc[2][j], v3 = sacc[3][j];
        if (diag) {
          const int thr = rowq + j;
          if (fr > thr)      v0 = -INFINITY;
          if (16 + fr > thr) v1 = -INFINITY;
          if (32 + fr > thr) v2 = -INFINITY;
          if (48 + fr > thr) v3 = -INFINITY;
        }
        sv[j][0] = v0; sv[j][1] = v1; sv[j][2] = v2; sv[j][3] = v3;
        float pm = fmaxf(fmaxf(v0, v1), fmaxf(v2, v3));
        pm = fmaxf(pm, __shfl_xor(pm, 1, 64));
        pm = fmaxf(pm, __shfl_xor(pm, 2, 64));
        pm = fmaxf(pm, __shfl_xor(pm, 4, 64));
        pm = fmaxf(pm, __shfl_xor(pm, 8, 64));
        pmj[j] = pm;
      }

      // ---- defer-max: rescale only when some row max grew past THR=8 ----
      bool grow = false;
      #pragma unroll
      for (int j = 0; j < 4; ++j) grow |= (pmj[j] > mrow[j] + 8.0f);
      if (__any(grow)) {                       // wave-uniform branch
        float al[4];
        #pragma unroll
        for (int j = 0; j < 4; ++j) {
          const float mnew = fmaxf(mrow[j], pmj[j]);
          al[j] = __expf(mrow[j] - mnew);      // exp(-inf)=0 on first tile
          mrow[j] = mnew;
        }
        lacc[0] *= al[0]; lacc[1] *= al[1]; lacc[2] *= al[2]; lacc[3] *= al[3];
        #pragma unroll
        for (int db = 0; db < 4; ++db) {
          oacc[db][0] *= al[0]; oacc[db][1] *= al[1];
          oacc[db][2] *= al[2]; oacc[db][3] *= al[3];
        }
      }

      // ---- P = exp(S - m), write to LDS ----
      #pragma unroll
      for (int j = 0; j < 4; ++j) {
        short* prow = &Pl[wave][fk * 4 + j][fr];
        prow[0]  = f2bf(__expf(sv[j][0] - mrow[j]));
        prow[16] = f2bf(__expf(sv[j][1] - mrow[j]));
        prow[32] = f2bf(__expf(sv[j][2] - mrow[j]));
        prow[48] = f2bf(__expf(sv[j][3] - mrow[j]));
      }

      // ---- PV + row-sum via ones-column MFMA ----
      const bf16x8 ap0 = as_bf16x8(*(const s16x8*)&Pl[wave][fr][fk * 8]);
      const bf16x8 ap1 = as_bf16x8(*(const s16x8*)&Pl[wave][fr][32 + fk * 8]);
      unsigned long long t00, t01, t02, t03, t10, t11, t12, t13;
      unsigned long long t20, t21, t22, t23, t30, t31, t32, t33;
      TRREAD(t00, "0");    TRREAD(t01, "128");  TRREAD(t02, "1024"); TRREAD(t03, "1152");
      TRREAD(t10, "2080"); TRREAD(t11, "2208"); TRREAD(t12, "3104"); TRREAD(t13, "3232");
      TRREAD(t20, "4160"); TRREAD(t21, "4288"); TRREAD(t22, "5184"); TRREAD(t23, "5312");
      TRREAD(t30, "6240"); TRREAD(t31, "6368"); TRREAD(t32, "7264"); TRREAD(t33, "7392");
      asm volatile("s_waitcnt lgkmcnt(0)" ::: "memory");
      __builtin_amdgcn_sched_barrier(0);
      __builtin_amdgcn_s_setprio(1);
      lacc = __builtin_amdgcn_mfma_f32_16x16x32_bf16(ap0, ones, lacc, 0, 0, 0);
      lacc = __builtin_amdgcn_mfma_f32_16x16x32_bf16(ap1, ones, lacc, 0, 0, 0);
      oacc[0] = __builtin_amdgcn_mfma_f32_16x16x32_bf16(ap0, mk8(t00, t01), oacc[0], 0, 0, 0);
      oacc[0] = __builtin_amdgcn_mfma_f32_16x16x32_bf16(ap1, mk8(t02, t03), oacc[0], 0, 0, 0);
      oacc[1] = __builtin_amdgcn_mfma_f32_16x16x32_bf16(ap0, mk8(t10, t11), oacc[1], 0, 0, 0);
      oacc[1] = __builtin_amdgcn_mfma_f32_16x16x32_bf16(ap1, mk8(t12, t13), oacc[1], 0, 0, 0);
      oacc[2] = __builtin_amdgcn_mfma_f32_16x16x32_bf16(ap0, mk8(t20, t21), oacc[2], 0, 0, 0);
      oacc[2] = __builtin_amdgcn_mfma_f32_16x16x32_bf16(ap1, mk8(t22, t23), oacc[2], 0, 0, 0);
      oacc[3] = __builtin_amdgcn_mfma_f32_16x16x32_bf16(ap0, mk8(t30, t31), oacc[3], 0, 0, 0);
      oacc[3] = __builtin_amdgcn_mfma_f32_16x16x32_bf16(ap1, mk8(t32, t33), oacc[3], 0, 0, 0);
      __builtin_amdgcn_s_setprio(0);
      __syncthreads();
    }

    // ---- epilogue for this q-tile ----
    #pragma unroll
    for (int db = 0; db < 4; ++db)
      #pragma unroll
      for (int j = 0; j < 4; ++j) {
        const int qg = q0 + wave * 16 + fk * 4 + j;
        O[(size_t)(b * TLEN + qg) * EMBED + h * HD + db * 16 + fr] =
            f2bf(oacc[db][j] / lacc[j]);
      }
  }
#undef TRREAD
}

// ---------------------------------------------------------------------------
extern "C" void kernel_launch(void* const* d_in, const int* in_sizes, int n_in,
                              void* d_out, int out_size, void* d_ws, size_t ws_size,
                              hipStream_t stream) {
  const float* x  = (const float*)d_in[0];
  const float* Wq = (const float*)d_in[1];
  const float* bq = (const float*)d_in[2];
  const float* Wk = (const float*)d_in[3];
  const float* bk = (const float*)d_in[4];
  const float* Wv = (const float*)d_in[5];
  const float* bv = (const float*)d_in[6];
  const float* Wo = (const float*)d_in[7];
  const float* bo = (const float*)d_in[8];
  float* out = (float*)d_out;

  // ws layout (exactly 62,914,560 B = validated lower bound on ws_size):
  char* ws = (char*)d_ws;
  short* xb    = (short*)(ws);               // 16,777,216  [0 .. 16.78M)
  short* WqkvT = (short*)(ws + 16777216);    // 12,582,912  [16.78M .. 29.36M)
  short* WoT   = (short*)(ws + 29360128);    //  8,388,608  [29.36M .. 37.75M)
  short* QKV   = (short*)(ws + 37748736);    // 25,165,824  [37.75M .. 62.91M)
  short* Ob    = (short*)(ws);               // alias xb (dead after QKV GEMM)
  // RoPE table lives in the front of d_out (512 KB); final GEMM overwrites
  // all of d_out afterwards (R5 established early d_out scribbling is safe).
  float2* tab  = (float2*)d_out;

  dim3 tb(32, 8);
  transpose_cast_kernel<<<dim3(EMBED / 32, EMBED / 32), tb, 0, stream>>>(Wq, WqkvT, EMBED, EMBED);
  transpose_cast_kernel<<<dim3(KVD / 32, EMBED / 32), tb, 0, stream>>>(Wk, WqkvT + (size_t)2048 * 2048, EMBED, KVD);
  transpose_cast_kernel<<<dim3(KVD / 32, EMBED / 32), tb, 0, stream>>>(Wv, WqkvT + (size_t)2560 * 2048, EMBED, KVD);
  transpose_cast_kernel<<<dim3(EMBED / 32, EMBED / 32), tb, 0, stream>>>(Wo, WoT, EMBED, EMBED);
  cast_bf16_kernel<<<(MROWS * EMBED / 4) / 256, 256, 0, stream>>>(x, xb, MROWS * EMBED);
  rope_table_kernel<<<256, 256, 0, stream>>>(tab);

  // fused QKV projection: [4096][3072] bf16, row stride 3072
  gemm_bt<false, true><<<dim3(QKVN / 128, MROWS / 128), 256, 0, stream>>>(
      xb, WqkvT, bq, bk, bv, QKV, QKVN);

  // RoPE (inverse rotation); fold 1/sqrt(64) into Q
  rope_apply_kernel<<<(MROWS * (EMBED / 2)) / 256, 256, 0, stream>>>(
      QKV, EMBED, QKVN, 0.125f, tab);
  rope_apply_kernel<<<(MROWS * (KVD / 2)) / 256, 256, 0, stream>>>(
      QKV + 2048, KVD, QKVN, 1.0f, tab);

  attn_kernel<<<dim3(16, BSZ * NH), 256, 0, stream>>>(
      QKV, QKV + 2048, QKV + 2560, Ob);

  gemm_bt<true, false><<<dim3(EMBED / 128, MROWS / 128), 256, 0, stream>>>(
      Ob, WoT, bo, bo, bo, out, EMBED);
}

// Round 14
// 255.893 us; speedup vs baseline: 2.6841x; 1.0469x over previous
//
#include <hip/hip_runtime.h>
#include <hip/hip_bf16.h>
#include <stdint.h>
#include <stddef.h>

#define EMBED 2048
#define TLEN  2048
#define BSZ   2
#define NH    32
#define NKV   8
#define HD    64
#define MROWS (BSZ*TLEN)   // 4096
#define KVD   (NKV*HD)     // 512
#define QKVN  3072         // fused QKV column extent / row stride

typedef __attribute__((ext_vector_type(8))) short   s16x8;
typedef __attribute__((ext_vector_type(4))) short   s16x4;
typedef __attribute__((ext_vector_type(8))) __bf16  bf16x8;
typedef __attribute__((ext_vector_type(4))) float   f32x4;
typedef __attribute__((ext_vector_type(2))) unsigned long long u64x2;
typedef __attribute__((ext_vector_type(4))) uint32_t u32x4;

static __device__ __forceinline__ float bf2f(short u) {
  union { float f; uint32_t i; } c; c.i = ((uint32_t)(uint16_t)u) << 16; return c.f;
}
static __device__ __forceinline__ short f2bf(float f) {
  union { float f; uint32_t i; } c; c.f = f;
  uint32_t x = c.i;
  uint32_t r = (x + 0x7fffu + ((x >> 16) & 1u)) >> 16;  // RNE
  return (short)(uint16_t)r;
}
static __device__ __forceinline__ bf16x8 as_bf16x8(s16x8 s) {
  return __builtin_bit_cast(bf16x8, s);
}
static __device__ __forceinline__ bf16x8 mk8(unsigned long long a, unsigned long long b) {
  u64x2 t; t.x = a; t.y = b;
  return __builtin_bit_cast(bf16x8, t);
}
static __device__ __forceinline__ bf16x8 mk8w(uint32_t w0, uint32_t w1,
                                              uint32_t w2, uint32_t w3) {
  u32x4 t; t.x = w0; t.y = w1; t.z = w2; t.w = w3;
  return __builtin_bit_cast(bf16x8, t);
}

// ---------------------------------------------------------------------------
// W [K][N] fp32  ->  Wt [N][K] bf16 (dst base may carry a row offset)
__global__ __launch_bounds__(256) void transpose_cast_kernel(
    const float* __restrict__ W, short* __restrict__ Wt, int K, int N) {
  __shared__ float tile[32][33];
  int n0 = blockIdx.x * 32, k0 = blockIdx.y * 32;
  int tx = threadIdx.x, ty = threadIdx.y;   // 32 x 8
  #pragma unroll
  for (int i = 0; i < 32; i += 8)
    tile[ty + i][tx] = W[(size_t)(k0 + ty + i) * N + n0 + tx];
  __syncthreads();
  #pragma unroll
  for (int i = 0; i < 32; i += 8)
    Wt[(size_t)(n0 + ty + i) * K + k0 + tx] = f2bf(tile[tx][ty + i]);
}

// fp32 -> bf16 elementwise
__global__ __launch_bounds__(256) void cast_bf16_kernel(
    const float* __restrict__ in, short* __restrict__ out, int n) {
  int i = (blockIdx.x * blockDim.x + threadIdx.x) * 4;
  if (i >= n) return;
  f32x4 v = *(const f32x4*)(in + i);
  s16x4 o = { f2bf(v.x), f2bf(v.y), f2bf(v.z), f2bf(v.w) };
  *(s16x4*)(out + i) = o;
}

// ---------------------------------------------------------------------------
// C[M=4096][colN] = A[4096][2048] @ Bt[colN][2048]^T + bias; row stride ldc.
// 128x128 tile, BK=32, 4 waves, global_load_lds width=16 staging.
template<bool OUT_F32, bool TRIPLE_BIAS>
__global__ __launch_bounds__(256) void gemm_bt(
    const short* __restrict__ A, const short* __restrict__ Bt,
    const float* __restrict__ b0, const float* __restrict__ b1,
    const float* __restrict__ b2, void* __restrict__ Cout, int ldc) {
  const int K = 2048;
  __shared__ __align__(16) short As[128 * 32];
  __shared__ __align__(16) short Bs[128 * 32];
  int bn = blockIdx.x, bm = blockIdx.y;
  int tid = threadIdx.x;
  int lane = tid & 63, wave = tid >> 6;
  int wr = wave >> 1, wc = wave & 1;
  int fr = lane & 15, fk = lane >> 4;
  f32x4 acc[4][4] = {};
  const short* Ab = A + (size_t)bm * 128 * K;
  const short* Bb = Bt + (size_t)bn * 128 * K;
  for (int kt = 0; kt < K; kt += 32) {
    #pragma unroll
    for (int ii = 0; ii < 2; ++ii) {
      const int i = wave * 2 + ii;
      const int r = i * 16 + (lane >> 2);
      const int c = lane & 3;
      const size_t go = (size_t)r * K + kt + c * 8;
      __builtin_amdgcn_global_load_lds(
          (const __attribute__((address_space(1))) void*)(Ab + go),
          (__attribute__((address_space(3))) void*)&As[i * 512], 16, 0, 0);
      __builtin_amdgcn_global_load_lds(
          (const __attribute__((address_space(1))) void*)(Bb + go),
          (__attribute__((address_space(3))) void*)&Bs[i * 512], 16, 0, 0);
    }
    __syncthreads();
    bf16x8 af[4], bfr[4];
    #pragma unroll
    for (int m = 0; m < 4; ++m)
      af[m] = as_bf16x8(*(const s16x8*)&As[(wr * 64 + m * 16 + fr) * 32 + fk * 8]);
    #pragma unroll
    for (int n = 0; n < 4; ++n)
      bfr[n] = as_bf16x8(*(const s16x8*)&Bs[(wc * 64 + n * 16 + fr) * 32 + fk * 8]);
    __builtin_amdgcn_s_setprio(1);
    #pragma unroll
    for (int m = 0; m < 4; ++m)
      #pragma unroll
      for (int n = 0; n < 4; ++n)
        acc[m][n] = __builtin_amdgcn_mfma_f32_16x16x32_bf16(af[m], bfr[n], acc[m][n], 0, 0, 0);
    __builtin_amdgcn_s_setprio(0);
    __syncthreads();
  }
  int row0 = bm * 128 + wr * 64;
  int col0 = bn * 128 + wc * 64;
  #pragma unroll
  for (int n = 0; n < 4; ++n) {
    int col = col0 + n * 16 + fr;
    float bv;
    if constexpr (TRIPLE_BIAS)
      bv = (col < 2048) ? b0[col] : ((col < 2560) ? b1[col - 2048] : b2[col - 2560]);
    else
      bv = b0[col];
    #pragma unroll
    for (int m = 0; m < 4; ++m)
      #pragma unroll
      for (int j = 0; j < 4; ++j) {
        int row = row0 + m * 16 + fk * 4 + j;
        float v = acc[m][n][j] + bv;
        if constexpr (OUT_F32) ((float*)Cout)[(size_t)row * ldc + col] = v;
        else                   ((short*)Cout)[(size_t)row * ldc + col] = f2bf(v);
      }
  }
}

// ---------------------------------------------------------------------------
// RoPE cos/sin table: tab[t*32+i] = {cos, sin}(t * 10000^(-i/32))
__global__ __launch_bounds__(256) void rope_table_kernel(float2* __restrict__ tab) {
  int idx = blockIdx.x * 256 + threadIdx.x;       // 0..65535
  int t = idx >> 5, i = idx & 31;
  float ang = (float)t * powf(10000.0f, -(float)i / 32.0f);
  float c, s;
  sincosf(ang, &c, &s);
  tab[idx] = make_float2(c, s);
}

// Interleaved RoPE, INVERSE rotation (np reference convention, verified R11),
// table-driven, scale folded into output.
__global__ __launch_bounds__(256) void rope_apply_kernel(
    short* __restrict__ X, int ncols, int ldx, float oscale,
    const float2* __restrict__ tab) {
  int idx = blockIdx.x * 256 + threadIdx.x;
  int npr = ncols >> 1;
  int row = idx / npr, cp = idx - row * npr;
  int i = cp & 31;
  int t = row & (TLEN - 1);
  float2 cs = tab[(t << 5) | i];
  short* p = X + (size_t)row * ldx + cp * 2;
  float e = bf2f(p[0]), o = bf2f(p[1]);
  p[0] = f2bf((e * cs.x + o * cs.y) * oscale);
  p[1] = f2bf((o * cs.x - e * cs.y) * oscale);
}

// ---------------------------------------------------------------------------
// Flash attention, causal, GQA. 4 waves, 64 q-rows/block, KVBLK=64, q-tile
// pair (p, 31-p) per block. SWAPPED-OPERAND form: S^T = mfma(K, Q) so each
// lane owns one q-row (q = lane&15); softmax fully in-register; P assembled
// into B-fragments via cvt_pk + ds_bpermute; PV = mfma(V^T, P^T) -> O^T.
// Scores arrive in log2 domain (Q pre-scaled by 0.125*log2e); exp2 softmax.
__global__ __launch_bounds__(256) void attn_kernel(
    const short* __restrict__ Q, const short* __restrict__ Kx,
    const short* __restrict__ Vx, short* __restrict__ O) {
  const int pr = blockIdx.x;           // 0..15
  const int bh = blockIdx.y;           // 0..63
  const int b = bh >> 5, h = bh & 31, kvh = h >> 2;
  const int tid = threadIdx.x;
  const int lane = tid & 63, wave = tid >> 6;
  const int fr = lane & 15, fk = lane >> 4;

  __shared__ __align__(16) short Ks[64][72];    // [kpos][d], 2-way padded
  __shared__ __align__(16) short VS[4 * 1040];  // tr-read subtiled V

  const short* Kbase = Kx + (size_t)b * TLEN * QKVN + kvh * HD;
  const short* Vbase = Vx + (size_t)b * TLEN * QKVN + kvh * HD;

  const int srow = tid >> 3;
  const int scb  = (tid & 7) << 3;
  const int vd0  = scb >> 4;
  const int vco  = scb & 15;
  const unsigned trb = (unsigned)(unsigned long long)&VS[fk * 128 + fr * 4];
  const bf16x8 ones = mk8(0x3F803F803F803F80ULL, 0x3F803F803F803F80ULL);
  // bpermute source lanes (byte addresses): pair {2*(fk&1), 2*(fk&1)+1} x16 + fr
  const int src0 = (((fk & 1) << 5) + fr) << 2;   // lane 2*(fk&1)*16 + fr
  const int src1 = src0 + 64;                      // +16 lanes
  const bool msel = (fk >> 1) != 0;                // m-register select (fk>>1)

#define TRREAD(dst, OFF) asm volatile("ds_read_b64_tr_b16 %0, %1 offset:" OFF \
    : "=v"(dst) : "v"(trb) : "memory")
#define CVTPK(d, lo, hi) asm volatile("v_cvt_pk_bf16_f32 %0, %1, %2" \
    : "=v"(d) : "v"(lo), "v"(hi))

  #pragma unroll 1
  for (int rep = 0; rep < 2; ++rep) {
    const int qt = rep ? (31 - pr) : pr;
    const int q0 = qt * 64;
    const short* Qrow = Q + (size_t)(b * TLEN + q0 + wave * 16 + fr) * QKVN + h * HD;
    const bf16x8 aq0 = as_bf16x8(*(const s16x8*)&Qrow[fk * 8]);   // B-frag of Q^T
    const bf16x8 aq1 = as_bf16x8(*(const s16x8*)&Qrow[32 + fk * 8]);
    f32x4 oacc[4] = {};                 // O^T: col=q(=fr), rows d=db*16+fk*4+j
    f32x4 lacc = {};                    // row-sums per q (all regs identical)
    float m = -INFINITY;                // per-lane running max (log2 domain)
    const int qloc = wave * 16 + fr;    // q within 64-row block (for diag mask)

    for (int kv0 = 0; kv0 <= q0; kv0 += 64) {
      // ---- stage K (row-major padded) and V (tr-read subtiled) ----
      #pragma unroll
      for (int it = 0; it < 2; ++it) {
        const int r = srow + it * 32;
        const size_t gro = (size_t)(kv0 + r) * QKVN + scb;
        *(s16x8*)&Ks[r][scb] = *(const s16x8*)&Kbase[gro];
        s16x8 vv = *(const s16x8*)&Vbase[gro];
        *(s16x8*)&VS[vd0 * 1040 + ((r >> 2) << 6) + ((r & 3) << 4) + vco] = vv;
      }
      __syncthreads();

      // ---- S^T = K Q^T : 4 m-tiles (k-blocks of 16), K-dim = d = 64 ----
      f32x4 sacc[4] = {};
      {
        bf16x8 bk0[4], bk1[4];
        #pragma unroll
        for (int mb = 0; mb < 4; ++mb) {
          bk0[mb] = as_bf16x8(*(const s16x8*)&Ks[mb * 16 + fr][fk * 8]);
          bk1[mb] = as_bf16x8(*(const s16x8*)&Ks[mb * 16 + fr][32 + fk * 8]);
        }
        __builtin_amdgcn_s_setprio(1);
        #pragma unroll
        for (int mb = 0; mb < 4; ++mb) {
          sacc[mb] = __builtin_amdgcn_mfma_f32_16x16x32_bf16(bk0[mb], aq0, sacc[mb], 0, 0, 0);
          sacc[mb] = __builtin_amdgcn_mfma_f32_16x16x32_bf16(bk1[mb], aq1, sacc[mb], 0, 0, 0);
        }
        __builtin_amdgcn_s_setprio(0);
      }

      // ---- mask (diag only) + in-register row max ----
      const bool diag = (kv0 == q0);
      float sv[4][4];
      float pm = -INFINITY;
      #pragma unroll
      for (int mb = 0; mb < 4; ++mb)
        #pragma unroll
        for (int j = 0; j < 4; ++j) {
          float v = sacc[mb][j];
          if (diag && (mb * 16 + fk * 4 + j > qloc)) v = -INFINITY;
          sv[mb][j] = v;
          pm = fmaxf(pm, v);
        }
      pm = fmaxf(pm, __shfl_xor(pm, 16, 64));
      pm = fmaxf(pm, __shfl_xor(pm, 32, 64));

      // ---- defer-max rescale (THR = 11.5 in log2 domain ~= 8 nats) ----
      if (__any(pm > m + 11.5f)) {
        const float mnew = fmaxf(m, pm);
        const float al = exp2f(m - mnew);    // first tile: exp2(-inf)=0
        m = mnew;
        lacc[0] *= al; lacc[1] *= al; lacc[2] *= al; lacc[3] *= al;
        #pragma unroll
        for (int db = 0; db < 4; ++db) {
          oacc[db][0] *= al; oacc[db][1] *= al;
          oacc[db][2] *= al; oacc[db][3] *= al;
        }
      }

      // ---- P = exp2(S - m) in-register, pack to bf16 pairs ----
      uint32_t rlo[4], rhi[4];
      #pragma unroll
      for (int mb = 0; mb < 4; ++mb) {
        float p0 = exp2f(sv[mb][0] - m);
        float p1 = exp2f(sv[mb][1] - m);
        float p2 = exp2f(sv[mb][2] - m);
        float p3 = exp2f(sv[mb][3] - m);
        CVTPK(rlo[mb], p0, p1);
        CVTPK(rhi[mb], p2, p3);
      }

      // ---- assemble P^T B-fragments via bpermute (pull both m, select) ----
      uint32_t w0, w1, w2, w3, w4, w5, w6, w7;
      {
        uint32_t a, bq_;
        a = __builtin_amdgcn_ds_bpermute(src0, (int)rlo[0]);
        bq_ = __builtin_amdgcn_ds_bpermute(src0, (int)rlo[1]);
        w0 = msel ? bq_ : a;
        a = __builtin_amdgcn_ds_bpermute(src0, (int)rhi[0]);
        bq_ = __builtin_amdgcn_ds_bpermute(src0, (int)rhi[1]);
        w1 = msel ? bq_ : a;
        a = __builtin_amdgcn_ds_bpermute(src1, (int)rlo[0]);
        bq_ = __builtin_amdgcn_ds_bpermute(src1, (int)rlo[1]);
        w2 = msel ? bq_ : a;
        a = __builtin_amdgcn_ds_bpermute(src1, (int)rhi[0]);
        bq_ = __builtin_amdgcn_ds_bpermute(src1, (int)rhi[1]);
        w3 = msel ? bq_ : a;
        a = __builtin_amdgcn_ds_bpermute(src0, (int)rlo[2]);
        bq_ = __builtin_amdgcn_ds_bpermute(src0, (int)rlo[3]);
        w4 = msel ? bq_ : a;
        a = __builtin_amdgcn_ds_bpermute(src0, (int)rhi[2]);
        bq_ = __builtin_amdgcn_ds_bpermute(src0, (int)rhi[3]);
        w5 = msel ? bq_ : a;
        a = __builtin_amdgcn_ds_bpermute(src1, (int)rlo[2]);
        bq_ = __builtin_amdgcn_ds_bpermute(src1, (int)rlo[3]);
        w6 = msel ? bq_ : a;
        a = __builtin_amdgcn_ds_bpermute(src1, (int)rhi[2]);
        bq_ = __builtin_amdgcn_ds_bpermute(src1, (int)rhi[3]);
        w7 = msel ? bq_ : a;
      }
      const bf16x8 pB0 = mk8w(w0, w1, w2, w3);   // P^T[k=8fk..8fk+7][q=fr]
      const bf16x8 pB1 = mk8w(w4, w5, w6, w7);   // k = 32+8fk ..

      // ---- PV: O^T += V^T . P^T ; lsum += 1 . P^T ----
      unsigned long long t00, t01, t02, t03, t10, t11, t12, t13;
      unsigned long long t20, t21, t22, t23, t30, t31, t32, t33;
      TRREAD(t00, "0");    TRREAD(t01, "128");  TRREAD(t02, "1024"); TRREAD(t03, "1152");
      TRREAD(t10, "2080"); TRREAD(t11, "2208"); TRREAD(t12, "3104"); TRREAD(t13, "3232");
      TRREAD(t20, "4160"); TRREAD(t21, "4288"); TRREAD(t22, "5184"); TRREAD(t23, "5312");
      TRREAD(t30, "6240"); TRREAD(t31, "6368"); TRREAD(t32, "7264"); TRREAD(t33, "7392");
      asm volatile("s_waitcnt lgkmcnt(0)" ::: "memory");
      __builtin_amdgcn_sched_barrier(0);
      __builtin_amdgcn_s_setprio(1);
      lacc = __builtin_amdgcn_mfma_f32_16x16x32_bf16(ones, pB0, lacc, 0, 0, 0);
      lacc = __builtin_amdgcn_mfma_f32_16x16x32_bf16(ones, pB1, lacc, 0, 0, 0);
      oacc[0] = __builtin_amdgcn_mfma_f32_16x16x32_bf16(mk8(t00, t01), pB0, oacc[0], 0, 0, 0);
      oacc[0] = __builtin_amdgcn_mfma_f32_16x16x32_bf16(mk8(t02, t03), pB1, oacc[0], 0, 0, 0);
      oacc[1] = __builtin_amdgcn_mfma_f32_16x16x32_bf16(mk8(t10, t11), pB0, oacc[1], 0, 0, 0);
      oacc[1] = __builtin_amdgcn_mfma_f32_16x16x32_bf16(mk8(t12, t13), pB1, oacc[1], 0, 0, 0);
      oacc[2] = __builtin_amdgcn_mfma_f32_16x16x32_bf16(mk8(t20, t21), pB0, oacc[2], 0, 0, 0);
      oacc[2] = __builtin_amdgcn_mfma_f32_16x16x32_bf16(mk8(t22, t23), pB1, oacc[2], 0, 0, 0);
      oacc[3] = __builtin_amdgcn_mfma_f32_16x16x32_bf16(mk8(t30, t31), pB0, oacc[3], 0, 0, 0);
      oacc[3] = __builtin_amdgcn_mfma_f32_16x16x32_bf16(mk8(t32, t33), pB1, oacc[3], 0, 0, 0);
      __builtin_amdgcn_s_setprio(0);
      __syncthreads();
    }

    // ---- epilogue: O^T -> O, one q-row per lane, s16x4 packed stores ----
    {
      const float linv = 1.0f / lacc[0];
      short* orow = O + (size_t)(b * TLEN + q0 + wave * 16 + fr) * EMBED + h * HD + fk * 4;
      #pragma unroll
      for (int db = 0; db < 4; ++db) {
        s16x4 o4 = { f2bf(oacc[db][0] * linv), f2bf(oacc[db][1] * linv),
                     f2bf(oacc[db][2] * linv), f2bf(oacc[db][3] * linv) };
        *(s16x4*)&orow[db * 16] = o4;
      }
    }
  }
#undef TRREAD
#undef CVTPK
}

// ---------------------------------------------------------------------------
extern "C" void kernel_launch(void* const* d_in, const int* in_sizes, int n_in,
                              void* d_out, int out_size, void* d_ws, size_t ws_size,
                              hipStream_t stream) {
  const float* x  = (const float*)d_in[0];
  const float* Wq = (const float*)d_in[1];
  const float* bq = (const float*)d_in[2];
  const float* Wk = (const float*)d_in[3];
  const float* bk = (const float*)d_in[4];
  const float* Wv = (const float*)d_in[5];
  const float* bv = (const float*)d_in[6];
  const float* Wo = (const float*)d_in[7];
  const float* bo = (const float*)d_in[8];
  float* out = (float*)d_out;

  char* ws = (char*)d_ws;
  short* xb    = (short*)(ws);               // 16,777,216
  short* WqkvT = (short*)(ws + 16777216);    // 12,582,912
  short* WoT   = (short*)(ws + 29360128);    //  8,388,608
  short* QKV   = (short*)(ws + 37748736);    // 25,165,824
  short* Ob    = (short*)(ws);               // alias xb (dead after QKV GEMM)
  float2* tab  = (float2*)d_out;             // 512 KB scratch; overwritten at end

  dim3 tb(32, 8);
  transpose_cast_kernel<<<dim3(EMBED / 32, EMBED / 32), tb, 0, stream>>>(Wq, WqkvT, EMBED, EMBED);
  transpose_cast_kernel<<<dim3(KVD / 32, EMBED / 32), tb, 0, stream>>>(Wk, WqkvT + (size_t)2048 * 2048, EMBED, KVD);
  transpose_cast_kernel<<<dim3(KVD / 32, EMBED / 32), tb, 0, stream>>>(Wv, WqkvT + (size_t)2560 * 2048, EMBED, KVD);
  transpose_cast_kernel<<<dim3(EMBED / 32, EMBED / 32), tb, 0, stream>>>(Wo, WoT, EMBED, EMBED);
  cast_bf16_kernel<<<(MROWS * EMBED / 4) / 256, 256, 0, stream>>>(x, xb, MROWS * EMBED);
  rope_table_kernel<<<256, 256, 0, stream>>>(tab);

  gemm_bt<false, true><<<dim3(QKVN / 128, MROWS / 128), 256, 0, stream>>>(
      xb, WqkvT, bq, bk, bv, QKV, QKVN);

  // Q scale = 1/sqrt(64) * log2(e): softmax runs in exp2 domain
  rope_apply_kernel<<<(MROWS * (EMBED / 2)) / 256, 256, 0, stream>>>(
      QKV, EMBED, QKVN, 0.125f * 1.44269504088896340736f, tab);
  rope_apply_kernel<<<(MROWS * (KVD / 2)) / 256, 256, 0, stream>>>(
      QKV + 2048, KVD, QKVN, 1.0f, tab);

  attn_kernel<<<dim3(16, BSZ * NH), 256, 0, stream>>>(
      QKV, QKV + 2048, QKV + 2560, Ob);

  gemm_bt<true, false><<<dim3(EMBED / 128, MROWS / 128), 256, 0, stream>>>(
      Ob, WoT, bo, bo, bo, out, EMBED);
}